// Round 10
// baseline (132.053 us; speedup 1.0000x reference)
//
#include <hip/hip_runtime.h>
#include <hip/hip_bf16.h>

#define N_ 4096
#define D_ 768
#define NCLS 128
#define BM 128
#define BN 128
#define BKB 128   // K-bytes per step (fp8: 128 elems)
#define NSTEP 6   // D_/BKB

typedef float f32x4 __attribute__((ext_vector_type(4)));

// Normalize both embeddings to OCP fp8 e4m3 (blocks [0,N)->img, [N,2N)->txt).
__global__ __launch_bounds__(192) void normalize_kernel(
    const float* __restrict__ img, const float* __restrict__ txt,
    unsigned char* __restrict__ img_f8, unsigned char* __restrict__ txt_f8) {
  int b = blockIdx.x;
  const float* s;
  unsigned char* d;
  if (b < N_) {
    s = img + (size_t)b * D_;
    d = img_f8 + (size_t)b * D_;
  } else {
    s = txt + (size_t)(b - N_) * D_;
    d = txt_f8 + (size_t)(b - N_) * D_;
  }
  int tid = threadIdx.x;
  float4 v = ((const float4*)s)[tid];
  float ss = v.x * v.x + v.y * v.y + v.z * v.z + v.w * v.w;
#pragma unroll
  for (int m = 32; m; m >>= 1) ss += __shfl_xor(ss, m);
  __shared__ float wsum[3];
  int lane = tid & 63, w = tid >> 6;
  if (lane == 0) wsum[w] = ss;
  __syncthreads();
  float inv = 1.0f / fmaxf(sqrtf(wsum[0] + wsum[1] + wsum[2]), 1e-8f);
  int r = 0;
  r = __builtin_amdgcn_cvt_pk_fp8_f32(v.x * inv, v.y * inv, r, false);
  r = __builtin_amdgcn_cvt_pk_fp8_f32(v.z * inv, v.w * inv, r, true);
  ((int*)d)[tid] = r;
}

// 128x128-tile fp8 GEMM, r7's exact staging idioms (measured 0 conflicts):
// rows stored in global k-order, ds_write_b128 per (thread,j) at slot gq^(row&7);
// fragment loads are ds_read_b64 at slot (2ks+(g>>1))^(fr&7), half (g&1)*8
// = global k-bytes [ks*32+g*8, +8) (fp8 mfma lane k-mapping k=(lane>>4)*8+j).
// BK=128 fp8 -> 6 steps, 64 MFMA/step/wave. VGPR staging + reg prefetch.
__global__ __launch_bounds__(256) void gemm_epi_kernel(
    const unsigned char* __restrict__ A, const unsigned char* __restrict__ B,
    const int* __restrict__ labels, float* __restrict__ row_part,
    float* __restrict__ col_part, float* __restrict__ S_part) {
  __shared__ __align__(16) unsigned char As[16384];  // 128 rows x 128B
  __shared__ __align__(16) unsigned char Bs[16384];
  __shared__ int labR[BM], labC[BN];
  __shared__ float rbuf[2][BM], cbuf[2][BN];
  __shared__ float sbuf[4];

  const int bx = blockIdx.x, by = blockIdx.y;
  const int tid = threadIdx.x;
  const int lane = tid & 63, wave = tid >> 6;
  const int wr = wave >> 1, wc = wave & 1;
  const int g = lane >> 4, fr = lane & 15;
  const int rowBase = by * BM, colBase = bx * BN;

  if (tid < BM) labR[tid] = labels[rowBase + tid];
  else labC[tid - BM] = labels[colBase + tid - BM];

  // staging: thread t covers 16B chunk gq=t&7 of rows rbase+32j (j=0..3)
  const int gq = tid & 7, rbase = tid >> 3;  // rbase 0..31
  const unsigned char* pa = A + (size_t)(rowBase + rbase) * D_ + gq * 16;
  const unsigned char* pb = B + (size_t)(colBase + rbase) * D_ + gq * 16;
  const int wpos = rbase * 128 + (gq ^ (rbase & 7)) * 16;  // + j*4096 for rows +32j

  f32x4 acc[4][4] = {};

  // prologue: step 0 into regs
  uint4 ra[4], rb[4];
#pragma unroll
  for (int j = 0; j < 4; ++j) {
    ra[j] = *(const uint4*)(pa + (size_t)(32 * j) * D_);
    rb[j] = *(const uint4*)(pb + (size_t)(32 * j) * D_);
  }

  for (int u = 0; u < NSTEP; ++u) {
    __syncthreads();  // all waves done reading LDS from previous step
#pragma unroll
    for (int j = 0; j < 4; ++j) {
      *(uint4*)&As[wpos + j * 4096] = ra[j];
      *(uint4*)&Bs[wpos + j * 4096] = rb[j];
    }
    if (u + 1 < NSTEP) {  // prefetch next step; lands during MFMA below
      const int k0 = (u + 1) * BKB;
#pragma unroll
      for (int j = 0; j < 4; ++j) {
        ra[j] = *(const uint4*)(pa + (size_t)(32 * j) * D_ + k0);
        rb[j] = *(const uint4*)(pb + (size_t)(32 * j) * D_ + k0);
      }
    }
    __syncthreads();  // tile u resident
    const int sb = (g & 1) * 8;
    const int fx = fr & 7;
#pragma unroll
    for (int ks = 0; ks < 4; ++ks) {
      const int slot = ((ks << 1) + (g >> 1)) ^ fx;
      long bq[4];
#pragma unroll
      for (int n = 0; n < 4; ++n)
        bq[n] = *(const long*)&Bs[(wc * 64 + n * 16 + fr) * 128 + slot * 16 + sb];
#pragma unroll
      for (int m = 0; m < 4; ++m) {
        long aq = *(const long*)&As[(wr * 64 + m * 16 + fr) * 128 + slot * 16 + sb];
#pragma unroll
        for (int n = 0; n < 4; ++n)
          acc[m][n] = __builtin_amdgcn_mfma_f32_16x16x32_fp8_fp8(aq, bq[n], acc[m][n], 0, 0, 0);
      }
    }
  }
  __syncthreads();

  const float scale = 14.285714285714286f;  // 1/0.07
  float sPart = 0.f;
  float colAcc[4] = {0.f, 0.f, 0.f, 0.f};
#pragma unroll
  for (int m = 0; m < 4; ++m) {
    float ra2[4] = {0.f, 0.f, 0.f, 0.f};
#pragma unroll
    for (int n = 0; n < 4; ++n) {
      int col = wc * 64 + n * 16 + fr;
      int lc = labC[col];
#pragma unroll
      for (int r = 0; r < 4; ++r) {
        float v = acc[m][n][r] * scale;
        float e = __expf(v);
        ra2[r] += e;
        colAcc[n] += e;
        int row = wr * 64 + m * 16 + g * 4 + r;
        if (labR[row] == lc) sPart += v;
      }
    }
#pragma unroll
    for (int r = 0; r < 4; ++r) {
      float x = ra2[r];
      x += __shfl_xor(x, 1);
      x += __shfl_xor(x, 2);
      x += __shfl_xor(x, 4);
      x += __shfl_xor(x, 8);
      if (fr == 0) rbuf[wc][wr * 64 + m * 16 + g * 4 + r] = x;
    }
  }
#pragma unroll
  for (int n = 0; n < 4; ++n) {
    float x = colAcc[n];
    x += __shfl_xor(x, 16);
    x += __shfl_xor(x, 32);
    if (g == 0) cbuf[wr][wc * 64 + n * 16 + fr] = x;
  }
  float s = sPart;
#pragma unroll
  for (int m = 32; m; m >>= 1) s += __shfl_xor(s, m);
  if (lane == 0) sbuf[wave] = s;
  __syncthreads();
  if (tid < BM)
    row_part[(size_t)bx * N_ + rowBase + tid] = rbuf[0][tid] + rbuf[1][tid];
  else
    col_part[(size_t)by * N_ + colBase + (tid - BM)] = cbuf[0][tid - BM] + cbuf[1][tid - BM];
  if (tid == 0) S_part[by * 32 + bx] = sbuf[0] + sbuf[1] + sbuf[2] + sbuf[3];
}

// Per-block local histogram; partials out (no atomics, no memset needed)
__global__ __launch_bounds__(256) void reduce_kernel(
    const float* __restrict__ row_part, const float* __restrict__ col_part,
    const float* __restrict__ S_part, const int* __restrict__ labels,
    double* __restrict__ partials) {
  __shared__ int hist[NCLS];
  int tid = threadIdx.x;
  if (tid < NCLS) hist[tid] = 0;
  __syncthreads();
  for (int j = tid; j < N_; j += 256) atomicAdd(&hist[labels[j]], 1);
  __syncthreads();

  int i = blockIdx.x * 256 + tid;  // 0..4095
  float rs = 0.f, cs = 0.f;
#pragma unroll
  for (int b = 0; b < 32; ++b) {
    rs += row_part[(size_t)b * N_ + i];
    cs += col_part[(size_t)b * N_ + i];
  }
  int cnt = hist[labels[i]];
  double term = (double)cnt * ((double)logf(rs) + (double)logf(cs));
  double sterm = (i < 1024) ? (double)S_part[i] : 0.0;
#pragma unroll
  for (int m = 32; m; m >>= 1) {
    term += __shfl_xor(term, m);
    sterm += __shfl_xor(sterm, m);
  }
  __shared__ double tbuf[4], sb[4];
  int lane = tid & 63, w = tid >> 6;
  if (lane == 0) { tbuf[w] = term; sb[w] = sterm; }
  __syncthreads();
  if (tid == 0) {
    partials[blockIdx.x] = tbuf[0] + tbuf[1] + tbuf[2] + tbuf[3];
    partials[16 + blockIdx.x] = sb[0] + sb[1] + sb[2] + sb[3];
  }
}

__global__ void final_kernel(const double* __restrict__ partials, float* __restrict__ out) {
  double t = 0.0, s = 0.0;
#pragma unroll
  for (int i = 0; i < 16; ++i) {
    t += partials[i];
    s += partials[16 + i];
  }
  out[0] = (float)((t - 2.0 * s) / (2.0 * (double)N_));
}

extern "C" void kernel_launch(void* const* d_in, const int* in_sizes, int n_in,
                              void* d_out, int out_size, void* d_ws, size_t ws_size,
                              hipStream_t stream) {
  const float* img = (const float*)d_in[0];
  const float* txt = (const float*)d_in[1];
  const int* labels = (const int*)d_in[2];
  float* out = (float*)d_out;
  char* ws = (char*)d_ws;

  // workspace layout (bytes)
  unsigned char* img_f8 = (unsigned char*)(ws);            //  3,145,728
  unsigned char* txt_f8 = (unsigned char*)(ws + 3145728);  //  3,145,728
  float* row_part = (float*)(ws + 6291456);                //    524,288 (32 x 4096)
  float* col_part = (float*)(ws + 6815744);                //    524,288
  float* S_part = (float*)(ws + 7340032);                  //      4,096
  double* partials = (double*)(ws + 7344128);              //        256

  normalize_kernel<<<2 * N_, 192, 0, stream>>>(img, txt, img_f8, txt_f8);
  gemm_epi_kernel<<<dim3(32, 32), 256, 0, stream>>>(
      img_f8, txt_f8, labels, row_part, col_part, S_part);
  reduce_kernel<<<16, 256, 0, stream>>>(row_part, col_part, S_part, labels, partials);
  final_kernel<<<1, 1, 0, stream>>>(partials, out);
}

// Round 11
// 56.077 us; speedup vs baseline: 2.3549x; 2.3549x over previous
//
#include <hip/hip_runtime.h>
#include <hip/hip_bf16.h>

#define N_ 4096
#define D_ 768
#define NCLS 128
#define BM 128
#define BN 128
#define BK 64
#define NSTEP 12  // D_/BK

typedef __bf16 bf16x8 __attribute__((ext_vector_type(8)));
typedef float f32x4 __attribute__((ext_vector_type(4)));
typedef short s16x8 __attribute__((ext_vector_type(8)));

// Normalize both embedding matrices (blocks [0,N) -> img, [N,2N) -> txt).
__global__ __launch_bounds__(192) void normalize_kernel(
    const float* __restrict__ img, const float* __restrict__ txt,
    __hip_bfloat16* __restrict__ img_nb, __hip_bfloat16* __restrict__ txt_nb) {
  int b = blockIdx.x;
  const float* s;
  __hip_bfloat16* d;
  if (b < N_) {
    s = img + (size_t)b * D_;
    d = img_nb + (size_t)b * D_;
  } else {
    s = txt + (size_t)(b - N_) * D_;
    d = txt_nb + (size_t)(b - N_) * D_;
  }
  int tid = threadIdx.x;
  float4 v = ((const float4*)s)[tid];
  float ss = v.x * v.x + v.y * v.y + v.z * v.z + v.w * v.w;
#pragma unroll
  for (int m = 32; m; m >>= 1) ss += __shfl_xor(ss, m);
  __shared__ float wsum[3];
  int lane = tid & 63, w = tid >> 6;
  if (lane == 0) wsum[w] = ss;
  __syncthreads();
  float inv = 1.0f / fmaxf(sqrtf(wsum[0] + wsum[1] + wsum[2]), 1e-8f);
  ushort4 o;
  o.x = __bfloat16_as_ushort(__float2bfloat16(v.x * inv));
  o.y = __bfloat16_as_ushort(__float2bfloat16(v.y * inv));
  o.z = __bfloat16_as_ushort(__float2bfloat16(v.z * inv));
  o.w = __bfloat16_as_ushort(__float2bfloat16(v.w * inv));
  ((ushort4*)d)[tid] = o;
}

// 128x128-tile bf16 GEMM, r7's exact (measured-0-conflict) LDS idioms, now
// DOUBLE-buffered with ONE barrier per K-step:
//   step u: [barrier] ds_write buf[(u+1)&1] <- regs(u+1 data, loaded last step);
//           ds_read buf[u&1] + 32 MFMA; global load regs <- step u+2.
// Writes go to the buffer whose reads completed before the previous barrier
// (safe); reads of buf[u&1] don't depend on the writes (other buffer).
// Global latency gets ~1 full step; WAR on staging regs spans the MFMA block.
__global__ __launch_bounds__(256) void gemm_epi_kernel(
    const unsigned short* __restrict__ A, const unsigned short* __restrict__ B,
    const int* __restrict__ labels, float* __restrict__ row_part,
    float* __restrict__ col_part, float* __restrict__ S_part) {
  __shared__ __align__(16) unsigned short As[2][8192];  // 2 x 128 rows x 8 chunks x 8
  __shared__ __align__(16) unsigned short Bs[2][8192];
  __shared__ int labR[BM], labC[BN];
  __shared__ float rbuf[2][BM], cbuf[2][BN];
  __shared__ float sbuf[4];

  const int bx = blockIdx.x, by = blockIdx.y;
  const int tid = threadIdx.x;
  const int lane = tid & 63, wave = tid >> 6;
  const int wr = wave >> 1, wc = wave & 1;
  const int g = lane >> 4, fr = lane & 15;
  const int rowBase = by * BM, colBase = bx * BN;

  if (tid < BM) labR[tid] = labels[rowBase + tid];
  else labC[tid - BM] = labels[colBase + tid - BM];

  // staging: thread t covers chunk col gq=t&7, rows rbase+32j (j=0..3)
  const int gq = tid & 7, rbase = tid >> 3;  // rbase 0..31
  const unsigned short* pa = A + (size_t)(rowBase + rbase) * D_ + gq * 8;
  const unsigned short* pb = B + (size_t)(colBase + rbase) * D_ + gq * 8;
  const int wpos = (rbase * 8 + (gq ^ (rbase & 7))) * 8;  // + j*2048 for rows +32j

  f32x4 acc[4][4] = {};

  // prologue: write step 0 into buf0; load step 1 into regs
  s16x8 ra[4], rb[4];
#pragma unroll
  for (int j = 0; j < 4; ++j) {
    ra[j] = *(const s16x8*)(pa + (size_t)(32 * j) * D_);
    rb[j] = *(const s16x8*)(pb + (size_t)(32 * j) * D_);
  }
#pragma unroll
  for (int j = 0; j < 4; ++j) {
    *(s16x8*)&As[0][wpos + j * 2048] = ra[j];
    *(s16x8*)&Bs[0][wpos + j * 2048] = rb[j];
  }
#pragma unroll
  for (int j = 0; j < 4; ++j) {
    ra[j] = *(const s16x8*)(pa + (size_t)(32 * j) * D_ + BK);
    rb[j] = *(const s16x8*)(pb + (size_t)(32 * j) * D_ + BK);
  }
  __syncthreads();  // buf0 resident

  for (int u = 0; u < NSTEP; ++u) {
    // write step u+1 into the other buffer (its readers finished last step)
    if (u + 1 < NSTEP) {
      unsigned short* aw = As[(u + 1) & 1];
      unsigned short* bw = Bs[(u + 1) & 1];
#pragma unroll
      for (int j = 0; j < 4; ++j) {
        *(s16x8*)&aw[wpos + j * 2048] = ra[j];
        *(s16x8*)&bw[wpos + j * 2048] = rb[j];
      }
    }
    const unsigned short* as_ = As[u & 1];
    const unsigned short* bs_ = Bs[u & 1];
#pragma unroll
    for (int ks = 0; ks < 2; ++ks) {
      const int sw = (ks * 4 + g) ^ (fr & 7);  // swizzled chunk col; row&7 == fr&7
      bf16x8 af[4], bf[4];
#pragma unroll
      for (int m = 0; m < 4; ++m)
        af[m] = *(const bf16x8*)&as_[((wr * 64 + m * 16 + fr) * 8 + sw) * 8];
#pragma unroll
      for (int n = 0; n < 4; ++n)
        bf[n] = *(const bf16x8*)&bs_[((wc * 64 + n * 16 + fr) * 8 + sw) * 8];
#pragma unroll
      for (int m = 0; m < 4; ++m)
#pragma unroll
        for (int n = 0; n < 4; ++n)
          acc[m][n] = __builtin_amdgcn_mfma_f32_16x16x32_bf16(af[m], bf[n], acc[m][n], 0, 0, 0);
    }
    // load step u+2 into staging regs (WAR gap spans the MFMA block above)
    if (u + 2 < NSTEP) {
      const int k0 = (u + 2) * BK;
#pragma unroll
      for (int j = 0; j < 4; ++j) {
        ra[j] = *(const s16x8*)(pa + (size_t)(32 * j) * D_ + k0);
        rb[j] = *(const s16x8*)(pb + (size_t)(32 * j) * D_ + k0);
      }
    }
    __syncthreads();  // writes of u+1 complete; all reads of u complete
  }

  const float scale = 14.285714285714286f;  // 1/0.07
  float sPart = 0.f;
  float colAcc[4] = {0.f, 0.f, 0.f, 0.f};
#pragma unroll
  for (int m = 0; m < 4; ++m) {
    float ra2[4] = {0.f, 0.f, 0.f, 0.f};
#pragma unroll
    for (int n = 0; n < 4; ++n) {
      int col = wc * 64 + n * 16 + fr;
      int lc = labC[col];
#pragma unroll
      for (int r = 0; r < 4; ++r) {
        float v = acc[m][n][r] * scale;
        float e = __expf(v);
        ra2[r] += e;
        colAcc[n] += e;
        int row = wr * 64 + m * 16 + g * 4 + r;
        if (labR[row] == lc) sPart += v;
      }
    }
#pragma unroll
    for (int r = 0; r < 4; ++r) {
      float x = ra2[r];
      x += __shfl_xor(x, 1);
      x += __shfl_xor(x, 2);
      x += __shfl_xor(x, 4);
      x += __shfl_xor(x, 8);
      if (fr == 0) rbuf[wc][wr * 64 + m * 16 + g * 4 + r] = x;
    }
  }
#pragma unroll
  for (int n = 0; n < 4; ++n) {
    float x = colAcc[n];
    x += __shfl_xor(x, 16);
    x += __shfl_xor(x, 32);
    if (g == 0) cbuf[wr][wc * 64 + n * 16 + fr] = x;
  }
  float s = sPart;
#pragma unroll
  for (int m = 32; m; m >>= 1) s += __shfl_xor(s, m);
  if (lane == 0) sbuf[wave] = s;
  __syncthreads();
  if (tid < BM)
    row_part[(size_t)bx * N_ + rowBase + tid] = rbuf[0][tid] + rbuf[1][tid];
  else
    col_part[(size_t)by * N_ + colBase + (tid - BM)] = cbuf[0][tid - BM] + cbuf[1][tid - BM];
  if (tid == 0) S_part[by * 32 + bx] = sbuf[0] + sbuf[1] + sbuf[2] + sbuf[3];
}

// Per-block local histogram; partials out (no atomics, no memset needed)
__global__ __launch_bounds__(256) void reduce_kernel(
    const float* __restrict__ row_part, const float* __restrict__ col_part,
    const float* __restrict__ S_part, const int* __restrict__ labels,
    double* __restrict__ partials) {
  __shared__ int hist[NCLS];
  int tid = threadIdx.x;
  if (tid < NCLS) hist[tid] = 0;
  __syncthreads();
  for (int j = tid; j < N_; j += 256) atomicAdd(&hist[labels[j]], 1);
  __syncthreads();

  int i = blockIdx.x * 256 + tid;  // 0..4095
  float rs = 0.f, cs = 0.f;
#pragma unroll
  for (int b = 0; b < 32; ++b) {
    rs += row_part[(size_t)b * N_ + i];
    cs += col_part[(size_t)b * N_ + i];
  }
  int cnt = hist[labels[i]];
  double term = (double)cnt * ((double)logf(rs) + (double)logf(cs));
  double sterm = (i < 1024) ? (double)S_part[i] : 0.0;
#pragma unroll
  for (int m = 32; m; m >>= 1) {
    term += __shfl_xor(term, m);
    sterm += __shfl_xor(sterm, m);
  }
  __shared__ double tbuf[4], sb[4];
  int lane = tid & 63, w = tid >> 6;
  if (lane == 0) { tbuf[w] = term; sb[w] = sterm; }
  __syncthreads();
  if (tid == 0) {
    partials[blockIdx.x] = tbuf[0] + tbuf[1] + tbuf[2] + tbuf[3];
    partials[16 + blockIdx.x] = sb[0] + sb[1] + sb[2] + sb[3];
  }
}

__global__ void final_kernel(const double* __restrict__ partials, float* __restrict__ out) {
  double t = 0.0, s = 0.0;
#pragma unroll
  for (int i = 0; i < 16; ++i) {
    t += partials[i];
    s += partials[16 + i];
  }
  out[0] = (float)((t - 2.0 * s) / (2.0 * (double)N_));
}

extern "C" void kernel_launch(void* const* d_in, const int* in_sizes, int n_in,
                              void* d_out, int out_size, void* d_ws, size_t ws_size,
                              hipStream_t stream) {
  const float* img = (const float*)d_in[0];
  const float* txt = (const float*)d_in[1];
  const int* labels = (const int*)d_in[2];
  float* out = (float*)d_out;
  char* ws = (char*)d_ws;

  // workspace layout (bytes)
  __hip_bfloat16* img_nb = (__hip_bfloat16*)(ws);             //  6,291,456
  __hip_bfloat16* txt_nb = (__hip_bfloat16*)(ws + 6291456);   //  6,291,456
  float* row_part = (float*)(ws + 12582912);                  //    524,288 (32 x 4096)
  float* col_part = (float*)(ws + 13107200);                  //    524,288
  float* S_part = (float*)(ws + 13631488);                    //      4,096
  double* partials = (double*)(ws + 13635584);                //        256

  normalize_kernel<<<2 * N_, 192, 0, stream>>>(img, txt, img_nb, txt_nb);
  gemm_epi_kernel<<<dim3(32, 32), 256, 0, stream>>>(
      (const unsigned short*)img_nb, (const unsigned short*)txt_nb, labels,
      row_part, col_part, S_part);
  reduce_kernel<<<16, 256, 0, stream>>>(row_part, col_part, S_part, labels, partials);
  final_kernel<<<1, 1, 0, stream>>>(partials, out);
}